// Round 2
// baseline (615.927 us; speedup 1.0000x reference)
//
#include <hip/hip_runtime.h>
#include <hip/hip_bf16.h>

#define N_NODES 10000
#define N_EDGES 30000
#define F_NODE  32
#define F_EDGE  8
#define EMB     64
#define HID     16
#define NGRAPH  64

// --- Edge MLP hidden layer for both conv0 and conv1/2 MLPs: A[e,h] = relu(ea @ w1 + b1)
__global__ void k_edge_hidden(const float* __restrict__ ea,
                              const float* __restrict__ w1a, const float* __restrict__ b1a,
                              const float* __restrict__ w1b, const float* __restrict__ b1b,
                              float* __restrict__ A0, float* __restrict__ A1) {
    int e = blockIdx.x * blockDim.x + threadIdx.x;
    if (e >= N_EDGES) return;
    float f[F_EDGE];
#pragma unroll
    for (int i = 0; i < F_EDGE; i++) f[i] = ea[e * F_EDGE + i];
#pragma unroll
    for (int h = 0; h < HID; h++) {
        float s0 = b1a[h];
        float s1 = b1b[h];
#pragma unroll
        for (int i = 0; i < F_EDGE; i++) {
            s0 += f[i] * w1a[i * HID + h];
            s1 += f[i] * w1b[i * HID + h];
        }
        A0[e * HID + h] = fmaxf(s0, 0.f);
        A1[e * HID + h] = fmaxf(s1, 0.f);
    }
}

// --- Per-node precompute, 4 nodes per block:
//   U[n,h,o]  = sum_i x[n,i] * w2[h, i*EMB+o]
//   XB[n,o]   = sum_i x[n,i] * b2[i*EMB+o]
template <int IN>
__global__ void k_precompute(const float* __restrict__ xin,
                             const float* __restrict__ w2,
                             const float* __restrict__ bb2,
                             float* __restrict__ U, float* __restrict__ XB) {
    int n0 = blockIdx.x * 4;           // N_NODES % 4 == 0
    __shared__ float xr[4][IN];
    int t = threadIdx.x;               // 256 threads
    for (int j = t; j < 4 * IN; j += 256) xr[j / IN][j % IN] = xin[(n0 + j / IN) * IN + j % IN];
    __syncthreads();
#pragma unroll
    for (int k = 0; k < 4; k++) {
        int idx = t + k * 256;         // 0..1023 = h*64+o
        int h = idx >> 6, o = idx & 63;
        const float* wrow = w2 + (size_t)h * (IN * EMB) + o;
        float s0 = 0.f, s1 = 0.f, s2 = 0.f, s3 = 0.f;
#pragma unroll
        for (int i = 0; i < IN; i++) {
            float w = wrow[i * EMB];
            s0 += xr[0][i] * w; s1 += xr[1][i] * w;
            s2 += xr[2][i] * w; s3 += xr[3][i] * w;
        }
        U[(size_t)(n0 + 0) * (HID * EMB) + idx] = s0;
        U[(size_t)(n0 + 1) * (HID * EMB) + idx] = s1;
        U[(size_t)(n0 + 2) * (HID * EMB) + idx] = s2;
        U[(size_t)(n0 + 3) * (HID * EMB) + idx] = s3;
    }
    {
        int j = t >> 6, o = t & 63;    // 256 threads = 4 nodes x 64 outputs
        float s = 0.f;
#pragma unroll
        for (int i = 0; i < IN; i++) s += xr[j][i] * bb2[i * EMB + o];
        XB[(n0 + j) * EMB + o] = s;
    }
}

// --- Edge gather + scatter: msg[e,o] = XB[src,o] + sum_h A[e,h]*U[src,h,o]; atomicAdd into AGG[dst,o]
__global__ void k_gather(const float* __restrict__ A, const float* __restrict__ U,
                         const float* __restrict__ XB,
                         const int* __restrict__ src, const int* __restrict__ dst,
                         float* __restrict__ AGG) {
    int e = blockIdx.x * (blockDim.x >> 6) + (threadIdx.x >> 6);
    if (e >= N_EDGES) return;
    int o = threadIdx.x & 63;
    int s = src[e], d = dst[e];
    float m = XB[s * EMB + o];
    const float* Ue = U + (size_t)s * (HID * EMB) + o;
    const float* Ae = A + e * HID;
#pragma unroll
    for (int h = 0; h < HID; h++) m += Ae[h] * Ue[h * EMB];
    atomicAdd(&AGG[d * EMB + o], m);
}

// --- Node update: X[n,o] = relu(AGG[n,o] + sum_i x[n,i]*root[i,o] + bias[o]); in-place safe (LDS-staged)
template <int IN>
__global__ void k_update(const float* __restrict__ xin, const float* __restrict__ AGG,
                         const float* __restrict__ root, const float* __restrict__ bias,
                         float* __restrict__ Xout) {
    int n = blockIdx.x;
    __shared__ float xr[IN];
    int t = threadIdx.x; // 64 threads
    if (t < IN) xr[t] = xin[n * IN + t];
    __syncthreads();
    float s = AGG[n * EMB + t] + bias[t];
#pragma unroll
    for (int i = 0; i < IN; i++) s += xr[i] * root[i * EMB + t];
    Xout[n * EMB + t] = fmaxf(s, 0.f);
}

// --- Global max pool (values post-ReLU >= 0: uint atomicMax on non-negative floats is order-preserving)
__global__ void k_pool(const float* __restrict__ X, const int* __restrict__ batch,
                       unsigned int* __restrict__ POOL) {
    int idx = blockIdx.x * blockDim.x + threadIdx.x;
    if (idx >= N_NODES * EMB) return;
    int n = idx >> 6;
    int g = batch[n];
    atomicMax(&POOL[g * EMB + (idx & 63)], __float_as_uint(X[idx]));
}

// --- Head: out[g] = (pooled[g]@lin0_w + lin0_b) @ lin1_w + lin1_b
__global__ void k_head(const float* __restrict__ POOL,
                       const float* __restrict__ l0w, const float* __restrict__ l0b,
                       const float* __restrict__ l1w, const float* __restrict__ l1b,
                       float* __restrict__ out) {
    __shared__ float P[NGRAPH * EMB];
    int t = threadIdx.x; // 64
    for (int k = 0; k < NGRAPH; k++) P[k * EMB + t] = POOL[k * EMB + t];
    __syncthreads();
    int g = t;
    float acc = l1b[0];
    for (int o2 = 0; o2 < EMB; o2++) {
        float h = l0b[o2];
        for (int o = 0; o < EMB; o++) h += P[g * EMB + o] * l0w[o * EMB + o2];
        acc += h * l1w[o2];
    }
    out[g] = acc;
}

extern "C" void kernel_launch(void* const* d_in, const int* in_sizes, int n_in,
                              void* d_out, int out_size, void* d_ws, size_t ws_size,
                              hipStream_t stream) {
    const float* x_p    = (const float*)d_in[0];
    const float* ea     = (const float*)d_in[2];
    const int*   eidx   = (const int*)d_in[4];
    const int*   batch  = (const int*)d_in[5];
    const float* nn0_w1 = (const float*)d_in[6];
    const float* nn0_b1 = (const float*)d_in[7];
    const float* nn0_w2 = (const float*)d_in[8];
    const float* nn0_b2 = (const float*)d_in[9];
    const float* nn1_w1 = (const float*)d_in[10];
    const float* nn1_b1 = (const float*)d_in[11];
    const float* nn1_w2 = (const float*)d_in[12];
    const float* nn1_b2 = (const float*)d_in[13];
    const float* root0  = (const float*)d_in[14];
    const float* bias0  = (const float*)d_in[15];
    const float* root1  = (const float*)d_in[16];
    const float* bias1  = (const float*)d_in[17];
    const float* root2  = (const float*)d_in[18];
    const float* bias2  = (const float*)d_in[19];
    const float* lin0_w = (const float*)d_in[20];
    const float* lin0_b = (const float*)d_in[21];
    const float* lin1_w = (const float*)d_in[22];
    const float* lin1_b = (const float*)d_in[23];

    const int* src = eidx;             // edge_index_p[0]
    const int* dst = eidx + N_EDGES;   // edge_index_p[1]

    // workspace layout (fp32), ~52.5 MB total
    char* ws = (char*)d_ws;
    float* A0   = (float*)ws;  ws += (size_t)N_EDGES * HID * 4;
    float* A1   = (float*)ws;  ws += (size_t)N_EDGES * HID * 4;
    float* U    = (float*)ws;  ws += (size_t)N_NODES * HID * EMB * 4;
    float* XB   = (float*)ws;  ws += (size_t)N_NODES * EMB * 4;
    float* X    = (float*)ws;  ws += (size_t)N_NODES * EMB * 4;
    float* AGG  = (float*)ws;  ws += (size_t)N_NODES * EMB * 4;
    float* POOL = (float*)ws;  ws += (size_t)NGRAPH * EMB * 4;

    // edge MLP hiddens for both MLPs (A1 shared by convs 1 & 2)
    k_edge_hidden<<<(N_EDGES + 127) / 128, 128, 0, stream>>>(ea, nn0_w1, nn0_b1, nn1_w1, nn1_b1, A0, A1);

    // ---- conv 0 (input x_p, F_NODE=32)
    k_precompute<F_NODE><<<N_NODES / 4, 256, 0, stream>>>(x_p, nn0_w2, nn0_b2, U, XB);
    hipMemsetAsync(AGG, 0, (size_t)N_NODES * EMB * 4, stream);
    k_gather<<<(N_EDGES + 3) / 4, 256, 0, stream>>>(A0, U, XB, src, dst, AGG);
    k_update<F_NODE><<<N_NODES, 64, 0, stream>>>(x_p, AGG, root0, bias0, X);

    // ---- conv 1 (input X, EMB=64)
    k_precompute<EMB><<<N_NODES / 4, 256, 0, stream>>>(X, nn1_w2, nn1_b2, U, XB);
    hipMemsetAsync(AGG, 0, (size_t)N_NODES * EMB * 4, stream);
    k_gather<<<(N_EDGES + 3) / 4, 256, 0, stream>>>(A1, U, XB, src, dst, AGG);
    k_update<EMB><<<N_NODES, 64, 0, stream>>>(X, AGG, root1, bias1, X);

    // ---- conv 2
    k_precompute<EMB><<<N_NODES / 4, 256, 0, stream>>>(X, nn1_w2, nn1_b2, U, XB);
    hipMemsetAsync(AGG, 0, (size_t)N_NODES * EMB * 4, stream);
    k_gather<<<(N_EDGES + 3) / 4, 256, 0, stream>>>(A1, U, XB, src, dst, AGG);
    k_update<EMB><<<N_NODES, 64, 0, stream>>>(X, AGG, root2, bias2, X);

    // ---- pool + head
    hipMemsetAsync(POOL, 0, (size_t)NGRAPH * EMB * 4, stream);
    k_pool<<<(N_NODES * EMB + 255) / 256, 256, 0, stream>>>(X, batch, (unsigned int*)POOL);
    k_head<<<1, 64, 0, stream>>>(POOL, lin0_w, lin0_b, lin1_w, lin1_b, (float*)d_out);
}

// Round 3
// 330.846 us; speedup vs baseline: 1.8617x; 1.8617x over previous
//
#include <hip/hip_runtime.h>
#include <hip/hip_bf16.h>

#define N_NODES 10000
#define N_EDGES 30000
#define F_NODE  32
#define F_EDGE  8
#define EMB     64
#define HID     16
#define NGRAPH  64
#define NPB     16   // nodes per precompute block; N_NODES % NPB == 0 (10000/16 = 625)

// --- Edge MLP hidden layer for both conv0 and conv1/2 MLPs: A[e,h] = relu(ea @ w1 + b1)
__global__ void k_edge_hidden(const float* __restrict__ ea,
                              const float* __restrict__ w1a, const float* __restrict__ b1a,
                              const float* __restrict__ w1b, const float* __restrict__ b1b,
                              float* __restrict__ A0, float* __restrict__ A1) {
    int e = blockIdx.x * blockDim.x + threadIdx.x;
    if (e >= N_EDGES) return;
    float f[F_EDGE];
#pragma unroll
    for (int i = 0; i < F_EDGE; i++) f[i] = ea[e * F_EDGE + i];
#pragma unroll
    for (int h = 0; h < HID; h++) {
        float s0 = b1a[h];
        float s1 = b1b[h];
#pragma unroll
        for (int i = 0; i < F_EDGE; i++) {
            s0 += f[i] * w1a[i * HID + h];
            s1 += f[i] * w1b[i * HID + h];
        }
        A0[e * HID + h] = fmaxf(s0, 0.f);
        A1[e * HID + h] = fmaxf(s1, 0.f);
    }
}

// --- Per-node precompute, NPB nodes per block, no LDS:
//   U[n,h,o] = sum_i x[n,i] * w2[h, i*EMB+o]     (x reads are wave-uniform -> s_load)
//   XB[n,o]  = sum_i x[n,i] * b2[i*EMB+o]
template <int IN>
__global__ void __launch_bounds__(256) k_precompute(const float* __restrict__ xin,
                             const float* __restrict__ w2,
                             const float* __restrict__ bb2,
                             float* __restrict__ U, float* __restrict__ XB) {
    int n0 = blockIdx.x * NPB;
    int t = threadIdx.x;               // 256 threads
#pragma unroll
    for (int k = 0; k < 4; k++) {
        int idx = t + k * 256;         // 0..1023 = h*64+o
        int h = idx >> 6, o = idx & 63;
        const float* wrow = w2 + (size_t)h * (IN * EMB) + o;
        float acc[NPB];
#pragma unroll
        for (int j = 0; j < NPB; j++) acc[j] = 0.f;
        for (int i = 0; i < IN; i += 4) {
            float w0 = wrow[(i + 0) * EMB];
            float w1 = wrow[(i + 1) * EMB];
            float w2v = wrow[(i + 2) * EMB];
            float w3 = wrow[(i + 3) * EMB];
#pragma unroll
            for (int j = 0; j < NPB; j++) {
                const float* xj = xin + (n0 + j) * IN + i;  // uniform addr -> SGPR loads
                float a = acc[j];
                a = fmaf(xj[0], w0, a);
                a = fmaf(xj[1], w1, a);
                a = fmaf(xj[2], w2v, a);
                a = fmaf(xj[3], w3, a);
                acc[j] = a;
            }
        }
#pragma unroll
        for (int j = 0; j < NPB; j++) U[(size_t)(n0 + j) * (HID * EMB) + idx] = acc[j];
    }
    // XB: NPB*64 work items over 256 threads
    for (int jj = t; jj < NPB * EMB; jj += 256) {
        int j = jj >> 6, o = jj & 63;
        float s = 0.f;
        for (int i = 0; i < IN; i++) s += xin[(n0 + j) * IN + i] * bb2[i * EMB + o];
        XB[(n0 + j) * EMB + o] = s;
    }
}

// --- Edge gather + scatter: msg[e,o] = XB[src,o] + sum_h A[e,h]*U[src,h,o]; atomicAdd into AGG[dst,o]
__global__ void k_gather(const float* __restrict__ A, const float* __restrict__ U,
                         const float* __restrict__ XB,
                         const int* __restrict__ src, const int* __restrict__ dst,
                         float* __restrict__ AGG) {
    int e = blockIdx.x * (blockDim.x >> 6) + (threadIdx.x >> 6);
    if (e >= N_EDGES) return;
    int o = threadIdx.x & 63;
    int s = src[e], d = dst[e];
    float m = XB[s * EMB + o];
    const float* Ue = U + (size_t)s * (HID * EMB) + o;
    const float* Ae = A + e * HID;
#pragma unroll
    for (int h = 0; h < HID; h++) m += Ae[h] * Ue[h * EMB];
    atomicAdd(&AGG[d * EMB + o], m);
}

// --- Node update: X[n,o] = relu(AGG[n,o] + sum_i x[n,i]*root[i,o] + bias[o]); in-place safe (LDS-staged)
template <int IN>
__global__ void k_update(const float* __restrict__ xin, const float* __restrict__ AGG,
                         const float* __restrict__ root, const float* __restrict__ bias,
                         float* __restrict__ Xout) {
    int n = blockIdx.x;
    __shared__ float xr[IN];
    int t = threadIdx.x; // 64 threads
    if (t < IN) xr[t] = xin[n * IN + t];
    __syncthreads();
    float s = AGG[n * EMB + t] + bias[t];
#pragma unroll
    for (int i = 0; i < IN; i++) s += xr[i] * root[i * EMB + t];
    Xout[n * EMB + t] = fmaxf(s, 0.f);
}

// --- Global max pool (values post-ReLU >= 0: uint atomicMax on non-negative floats is order-preserving)
__global__ void k_pool(const float* __restrict__ X, const int* __restrict__ batch,
                       unsigned int* __restrict__ POOL) {
    int idx = blockIdx.x * blockDim.x + threadIdx.x;
    if (idx >= N_NODES * EMB) return;
    int n = idx >> 6;
    int g = batch[n];
    atomicMax(&POOL[g * EMB + (idx & 63)], __float_as_uint(X[idx]));
}

// --- Head: out[g] = (pooled[g]@lin0_w + lin0_b) @ lin1_w + lin1_b
__global__ void k_head(const float* __restrict__ POOL,
                       const float* __restrict__ l0w, const float* __restrict__ l0b,
                       const float* __restrict__ l1w, const float* __restrict__ l1b,
                       float* __restrict__ out) {
    __shared__ float P[NGRAPH * EMB];
    int t = threadIdx.x; // 64
    for (int k = 0; k < NGRAPH; k++) P[k * EMB + t] = POOL[k * EMB + t];
    __syncthreads();
    int g = t;
    float acc = l1b[0];
    for (int o2 = 0; o2 < EMB; o2++) {
        float h = l0b[o2];
        for (int o = 0; o < EMB; o++) h += P[g * EMB + o] * l0w[o * EMB + o2];
        acc += h * l1w[o2];
    }
    out[g] = acc;
}

extern "C" void kernel_launch(void* const* d_in, const int* in_sizes, int n_in,
                              void* d_out, int out_size, void* d_ws, size_t ws_size,
                              hipStream_t stream) {
    const float* x_p    = (const float*)d_in[0];
    const float* ea     = (const float*)d_in[2];
    const int*   eidx   = (const int*)d_in[4];
    const int*   batch  = (const int*)d_in[5];
    const float* nn0_w1 = (const float*)d_in[6];
    const float* nn0_b1 = (const float*)d_in[7];
    const float* nn0_w2 = (const float*)d_in[8];
    const float* nn0_b2 = (const float*)d_in[9];
    const float* nn1_w1 = (const float*)d_in[10];
    const float* nn1_b1 = (const float*)d_in[11];
    const float* nn1_w2 = (const float*)d_in[12];
    const float* nn1_b2 = (const float*)d_in[13];
    const float* root0  = (const float*)d_in[14];
    const float* bias0  = (const float*)d_in[15];
    const float* root1  = (const float*)d_in[16];
    const float* bias1  = (const float*)d_in[17];
    const float* root2  = (const float*)d_in[18];
    const float* bias2  = (const float*)d_in[19];
    const float* lin0_w = (const float*)d_in[20];
    const float* lin0_b = (const float*)d_in[21];
    const float* lin1_w = (const float*)d_in[22];
    const float* lin1_b = (const float*)d_in[23];

    const int* src = eidx;             // edge_index_p[0]
    const int* dst = eidx + N_EDGES;   // edge_index_p[1]

    // workspace layout (fp32), ~52.5 MB total
    char* ws = (char*)d_ws;
    float* A0   = (float*)ws;  ws += (size_t)N_EDGES * HID * 4;
    float* A1   = (float*)ws;  ws += (size_t)N_EDGES * HID * 4;
    float* U    = (float*)ws;  ws += (size_t)N_NODES * HID * EMB * 4;
    float* XB   = (float*)ws;  ws += (size_t)N_NODES * EMB * 4;
    float* X    = (float*)ws;  ws += (size_t)N_NODES * EMB * 4;
    float* AGG  = (float*)ws;  ws += (size_t)N_NODES * EMB * 4;
    float* POOL = (float*)ws;  ws += (size_t)NGRAPH * EMB * 4;

    // edge MLP hiddens for both MLPs (A1 shared by convs 1 & 2)
    k_edge_hidden<<<(N_EDGES + 127) / 128, 128, 0, stream>>>(ea, nn0_w1, nn0_b1, nn1_w1, nn1_b1, A0, A1);

    // ---- conv 0 (input x_p, F_NODE=32)
    k_precompute<F_NODE><<<N_NODES / NPB, 256, 0, stream>>>(x_p, nn0_w2, nn0_b2, U, XB);
    hipMemsetAsync(AGG, 0, (size_t)N_NODES * EMB * 4, stream);
    k_gather<<<(N_EDGES + 3) / 4, 256, 0, stream>>>(A0, U, XB, src, dst, AGG);
    k_update<F_NODE><<<N_NODES, 64, 0, stream>>>(x_p, AGG, root0, bias0, X);

    // ---- conv 1 (input X, EMB=64)
    k_precompute<EMB><<<N_NODES / NPB, 256, 0, stream>>>(X, nn1_w2, nn1_b2, U, XB);
    hipMemsetAsync(AGG, 0, (size_t)N_NODES * EMB * 4, stream);
    k_gather<<<(N_EDGES + 3) / 4, 256, 0, stream>>>(A1, U, XB, src, dst, AGG);
    k_update<EMB><<<N_NODES, 64, 0, stream>>>(X, AGG, root1, bias1, X);

    // ---- conv 2
    k_precompute<EMB><<<N_NODES / NPB, 256, 0, stream>>>(X, nn1_w2, nn1_b2, U, XB);
    hipMemsetAsync(AGG, 0, (size_t)N_NODES * EMB * 4, stream);
    k_gather<<<(N_EDGES + 3) / 4, 256, 0, stream>>>(A1, U, XB, src, dst, AGG);
    k_update<EMB><<<N_NODES, 64, 0, stream>>>(X, AGG, root2, bias2, X);

    // ---- pool + head
    hipMemsetAsync(POOL, 0, (size_t)NGRAPH * EMB * 4, stream);
    k_pool<<<(N_NODES * EMB + 255) / 256, 256, 0, stream>>>(X, batch, (unsigned int*)POOL);
    k_head<<<1, 64, 0, stream>>>(POOL, lin0_w, lin0_b, lin1_w, lin1_b, (float*)d_out);
}

// Round 4
// 316.954 us; speedup vs baseline: 1.9433x; 1.0438x over previous
//
#include <hip/hip_runtime.h>
#include <hip/hip_bf16.h>

#define N_NODES 10000
#define N_EDGES 30000
#define F_NODE  32
#define F_EDGE  8
#define EMB     64
#define HID     16
#define NGRAPH  64
#define NPB     16   // nodes per precompute node-group; 10000 % 16 == 0

// --- Edge MLP hidden layer for both conv0 and conv1/2 MLPs: A[e,h] = relu(ea @ w1 + b1)
__global__ void k_edge_hidden(const float* __restrict__ ea,
                              const float* __restrict__ w1a, const float* __restrict__ b1a,
                              const float* __restrict__ w1b, const float* __restrict__ b1b,
                              float* __restrict__ A0, float* __restrict__ A1) {
    int e = blockIdx.x * blockDim.x + threadIdx.x;
    if (e >= N_EDGES) return;
    float f[F_EDGE];
#pragma unroll
    for (int i = 0; i < F_EDGE; i++) f[i] = ea[e * F_EDGE + i];
#pragma unroll
    for (int h = 0; h < HID; h++) {
        float s0 = b1a[h];
        float s1 = b1b[h];
#pragma unroll
        for (int i = 0; i < F_EDGE; i++) {
            s0 += f[i] * w1a[i * HID + h];
            s1 += f[i] * w1b[i * HID + h];
        }
        A0[e * HID + h] = fmaxf(s0, 0.f);
        A1[e * HID + h] = fmaxf(s1, 0.f);
    }
}

// --- Per-node precompute. Grid = (N_NODES/NPB)*4 blocks; low 2 bits of blockIdx pick the
//     256-wide output quarter (idx = k*256+t in [0,1024) = h*64+o). Also fuses:
//       * zeroing of AGG (each block zeroes its nodes' quarter)
//       * zeroing of POOL (conv-2 instance only, first 16 blocks)
//   U[n,h,o] = sum_i x[n,i] * w2[h, i*EMB+o]   (x reads wave-uniform -> scalar loads)
//   XB[n,o]  = sum_i x[n,i] * b2[i*EMB+o]
template <int IN, bool ZERO_POOL>
__global__ void __launch_bounds__(256) k_precompute(const float* __restrict__ xin,
                             const float* __restrict__ w2,
                             const float* __restrict__ bb2,
                             float* __restrict__ U, float* __restrict__ XB,
                             float* __restrict__ AGG, float* __restrict__ POOL) {
    int k  = blockIdx.x & 3;
    int n0 = (blockIdx.x >> 2) * NPB;
    int t  = threadIdx.x;                 // 256 threads
    AGG[n0 * EMB + k * 256 + t] = 0.f;    // 4 quarters x 256 = NPB*EMB slice
    if (ZERO_POOL && blockIdx.x < (NGRAPH * EMB) / 256) {
        POOL[blockIdx.x * 256 + t] = 0.f;
    }
    int idx = k * 256 + t;                // h*64+o
    int h = idx >> 6, o = idx & 63;
    const float* wrow = w2 + (size_t)h * (IN * EMB) + o;
    float acc[NPB];
#pragma unroll
    for (int j = 0; j < NPB; j++) acc[j] = 0.f;
    for (int i = 0; i < IN; i += 4) {
        float w0 = wrow[(i + 0) * EMB];
        float w1 = wrow[(i + 1) * EMB];
        float w2v = wrow[(i + 2) * EMB];
        float w3 = wrow[(i + 3) * EMB];
#pragma unroll
        for (int j = 0; j < NPB; j++) {
            const float* xj = xin + (n0 + j) * IN + i;  // uniform addr -> SGPR loads
            float a = acc[j];
            a = fmaf(xj[0], w0, a);
            a = fmaf(xj[1], w1, a);
            a = fmaf(xj[2], w2v, a);
            a = fmaf(xj[3], w3, a);
            acc[j] = a;
        }
    }
#pragma unroll
    for (int j = 0; j < NPB; j++) U[(size_t)(n0 + j) * (HID * EMB) + idx] = acc[j];
    // XB quarter: this block covers columns [k*16, k*16+16) for NPB nodes
    {
        int j = t >> 4, oo = k * 16 + (t & 15);
        float s = 0.f;
        for (int i = 0; i < IN; i++) s += xin[(n0 + j) * IN + i] * bb2[i * EMB + oo];
        XB[(n0 + j) * EMB + oo] = s;
    }
}

// --- Edge gather + scatter: msg[e,o] = XB[src,o] + sum_h A[e,h]*U[src,h,o]; atomicAdd into AGG[dst,o]
__global__ void k_gather(const float* __restrict__ A, const float* __restrict__ U,
                         const float* __restrict__ XB,
                         const int* __restrict__ src, const int* __restrict__ dst,
                         float* __restrict__ AGG) {
    int e = blockIdx.x * (blockDim.x >> 6) + (threadIdx.x >> 6);
    if (e >= N_EDGES) return;
    int o = threadIdx.x & 63;
    int s = src[e], d = dst[e];
    float m = XB[s * EMB + o];
    const float* Ue = U + (size_t)s * (HID * EMB) + o;
    const float* Ae = A + e * HID;
#pragma unroll
    for (int h = 0; h < HID; h++) m += Ae[h] * Ue[h * EMB];
    atomicAdd(&AGG[d * EMB + o], m);
}

// --- Node update, 4 nodes per 256-thread block; in-place safe (LDS-staged x).
//     X[n,o] = relu(AGG[n,o] + sum_i x[n,i]*root[i,o] + bias[o])
//     POOLING instance also does the global max pool (post-ReLU >= 0: uint atomicMax is order-preserving)
template <int IN, bool POOLING>
__global__ void k_update(const float* __restrict__ xin, const float* __restrict__ AGG,
                         const float* __restrict__ root, const float* __restrict__ bias,
                         const int* __restrict__ batch,
                         float* __restrict__ Xout, unsigned int* __restrict__ POOL) {
    int n0 = blockIdx.x * 4;
    __shared__ float xr[4][IN];
    for (int idx = threadIdx.x; idx < 4 * IN; idx += 256)
        xr[idx / IN][idx % IN] = xin[n0 * IN + idx];
    __syncthreads();
    int j = threadIdx.x >> 6, t = threadIdx.x & 63;
    int n = n0 + j;
    float s = AGG[n * EMB + t] + bias[t];
#pragma unroll
    for (int i = 0; i < IN; i++) s += xr[j][i] * root[i * EMB + t];
    s = fmaxf(s, 0.f);
    Xout[n * EMB + t] = s;
    if (POOLING) atomicMax(&POOL[batch[n] * EMB + t], __float_as_uint(s));
}

// --- Head: out[g] = (pooled[g]@lin0_w + lin0_b) @ lin1_w + lin1_b
__global__ void k_head(const float* __restrict__ POOL,
                       const float* __restrict__ l0w, const float* __restrict__ l0b,
                       const float* __restrict__ l1w, const float* __restrict__ l1b,
                       float* __restrict__ out) {
    __shared__ float P[NGRAPH * EMB];
    int t = threadIdx.x; // 64
    for (int k = 0; k < NGRAPH; k++) P[k * EMB + t] = POOL[k * EMB + t];
    __syncthreads();
    int g = t;
    float acc = l1b[0];
    for (int o2 = 0; o2 < EMB; o2++) {
        float h = l0b[o2];
        for (int o = 0; o < EMB; o++) h += P[g * EMB + o] * l0w[o * EMB + o2];
        acc += h * l1w[o2];
    }
    out[g] = acc;
}

extern "C" void kernel_launch(void* const* d_in, const int* in_sizes, int n_in,
                              void* d_out, int out_size, void* d_ws, size_t ws_size,
                              hipStream_t stream) {
    const float* x_p    = (const float*)d_in[0];
    const float* ea     = (const float*)d_in[2];
    const int*   eidx   = (const int*)d_in[4];
    const int*   batch  = (const int*)d_in[5];
    const float* nn0_w1 = (const float*)d_in[6];
    const float* nn0_b1 = (const float*)d_in[7];
    const float* nn0_w2 = (const float*)d_in[8];
    const float* nn0_b2 = (const float*)d_in[9];
    const float* nn1_w1 = (const float*)d_in[10];
    const float* nn1_b1 = (const float*)d_in[11];
    const float* nn1_w2 = (const float*)d_in[12];
    const float* nn1_b2 = (const float*)d_in[13];
    const float* root0  = (const float*)d_in[14];
    const float* bias0  = (const float*)d_in[15];
    const float* root1  = (const float*)d_in[16];
    const float* bias1  = (const float*)d_in[17];
    const float* root2  = (const float*)d_in[18];
    const float* bias2  = (const float*)d_in[19];
    const float* lin0_w = (const float*)d_in[20];
    const float* lin0_b = (const float*)d_in[21];
    const float* lin1_w = (const float*)d_in[22];
    const float* lin1_b = (const float*)d_in[23];

    const int* src = eidx;             // edge_index_p[0]
    const int* dst = eidx + N_EDGES;   // edge_index_p[1]

    // workspace layout (fp32), ~52.5 MB total
    char* ws = (char*)d_ws;
    float* A0   = (float*)ws;  ws += (size_t)N_EDGES * HID * 4;
    float* A1   = (float*)ws;  ws += (size_t)N_EDGES * HID * 4;
    float* U    = (float*)ws;  ws += (size_t)N_NODES * HID * EMB * 4;
    float* XB   = (float*)ws;  ws += (size_t)N_NODES * EMB * 4;
    float* X    = (float*)ws;  ws += (size_t)N_NODES * EMB * 4;
    float* AGG  = (float*)ws;  ws += (size_t)N_NODES * EMB * 4;
    float* POOL = (float*)ws;  ws += (size_t)NGRAPH * EMB * 4;

    const int PRE_GRID = (N_NODES / NPB) * 4;   // 2500
    const int UPD_GRID = N_NODES / 4;           // 2500

    // edge MLP hiddens for both MLPs (A1 shared by convs 1 & 2)
    k_edge_hidden<<<(N_EDGES + 127) / 128, 128, 0, stream>>>(ea, nn0_w1, nn0_b1, nn1_w1, nn1_b1, A0, A1);

    // ---- conv 0 (input x_p, F_NODE=32)
    k_precompute<F_NODE, false><<<PRE_GRID, 256, 0, stream>>>(x_p, nn0_w2, nn0_b2, U, XB, AGG, POOL);
    k_gather<<<(N_EDGES + 3) / 4, 256, 0, stream>>>(A0, U, XB, src, dst, AGG);
    k_update<F_NODE, false><<<UPD_GRID, 256, 0, stream>>>(x_p, AGG, root0, bias0, batch, X, (unsigned int*)POOL);

    // ---- conv 1 (input X, EMB=64)
    k_precompute<EMB, false><<<PRE_GRID, 256, 0, stream>>>(X, nn1_w2, nn1_b2, U, XB, AGG, POOL);
    k_gather<<<(N_EDGES + 3) / 4, 256, 0, stream>>>(A1, U, XB, src, dst, AGG);
    k_update<EMB, false><<<UPD_GRID, 256, 0, stream>>>(X, AGG, root1, bias1, batch, X, (unsigned int*)POOL);

    // ---- conv 2 (fused: POOL zeroing in precompute, max-pool in update)
    k_precompute<EMB, true><<<PRE_GRID, 256, 0, stream>>>(X, nn1_w2, nn1_b2, U, XB, AGG, POOL);
    k_gather<<<(N_EDGES + 3) / 4, 256, 0, stream>>>(A1, U, XB, src, dst, AGG);
    k_update<EMB, true><<<UPD_GRID, 256, 0, stream>>>(X, AGG, root2, bias2, batch, X, (unsigned int*)POOL);

    // ---- head
    k_head<<<1, 64, 0, stream>>>(POOL, lin0_w, lin0_b, lin1_w, lin1_b, (float*)d_out);
}

// Round 5
// 268.199 us; speedup vs baseline: 2.2965x; 1.1818x over previous
//
#include <hip/hip_runtime.h>
#include <hip/hip_bf16.h>

#define N_NODES 10000
#define N_EDGES 30000
#define F_NODE  32
#define F_EDGE  8
#define EMB     64
#define HID     16
#define NGRAPH  64
#define NPB     8    // nodes per precompute block; 10000 % 8 == 0 (grid 1250*4 = 5000)

// --- Edge MLP hidden layer for both conv0 and conv1/2 MLPs: A[e,h] = relu(ea @ w1 + b1)
__global__ void k_edge_hidden(const float* __restrict__ ea,
                              const float* __restrict__ w1a, const float* __restrict__ b1a,
                              const float* __restrict__ w1b, const float* __restrict__ b1b,
                              float* __restrict__ A0, float* __restrict__ A1) {
    int e = blockIdx.x * blockDim.x + threadIdx.x;
    if (e >= N_EDGES) return;
    float f[F_EDGE];
#pragma unroll
    for (int i = 0; i < F_EDGE; i++) f[i] = ea[e * F_EDGE + i];
#pragma unroll
    for (int h = 0; h < HID; h++) {
        float s0 = b1a[h];
        float s1 = b1b[h];
#pragma unroll
        for (int i = 0; i < F_EDGE; i++) {
            s0 += f[i] * w1a[i * HID + h];
            s1 += f[i] * w1b[i * HID + h];
        }
        A0[e * HID + h] = fmaxf(s0, 0.f);
        A1[e * HID + h] = fmaxf(s1, 0.f);
    }
}

// --- Per-node precompute. Grid = (N_NODES/NPB)*4; low 2 bits pick the 256-wide output
//     quarter (idx = k*256+t in [0,1024) = h*64+o). Fused: AGG zeroing, POOL zeroing (conv2).
//   U[n,h,o] = sum_i x[n,i] * w2[h, i*EMB+o]   (bf16 store, fp32 accumulate)
//   XB[n,o]  = sum_i x[n,i] * b2[i*EMB+o]      (fp32)
template <int IN, bool ZERO_POOL>
__global__ void __launch_bounds__(256) k_precompute(const float* __restrict__ xin,
                             const float* __restrict__ w2,
                             const float* __restrict__ bb2,
                             __hip_bfloat16* __restrict__ U, float* __restrict__ XB,
                             float* __restrict__ AGG, float* __restrict__ POOL) {
    int k  = blockIdx.x & 3;
    int n0 = (blockIdx.x >> 2) * NPB;
    int t  = threadIdx.x;                 // 256 threads
    if (k < (NPB * EMB) / 256)            // NPB=8 -> k<2 covers the 512-elem AGG slice
        AGG[n0 * EMB + k * 256 + t] = 0.f;
    if (ZERO_POOL && blockIdx.x < (NGRAPH * EMB) / 256) {
        POOL[blockIdx.x * 256 + t] = 0.f;
    }
    int idx = k * 256 + t;                // h*64+o
    int h = idx >> 6, o = idx & 63;
    const float* wrow = w2 + (size_t)h * (IN * EMB) + o;
    float acc[NPB];
#pragma unroll
    for (int j = 0; j < NPB; j++) acc[j] = 0.f;
    for (int i = 0; i < IN; i += 4) {
        float w0 = wrow[(i + 0) * EMB];
        float w1 = wrow[(i + 1) * EMB];
        float w2v = wrow[(i + 2) * EMB];
        float w3 = wrow[(i + 3) * EMB];
#pragma unroll
        for (int j = 0; j < NPB; j++) {
            const float* xj = xin + (n0 + j) * IN + i;  // uniform addr -> SGPR loads
            float a = acc[j];
            a = fmaf(xj[0], w0, a);
            a = fmaf(xj[1], w1, a);
            a = fmaf(xj[2], w2v, a);
            a = fmaf(xj[3], w3, a);
            acc[j] = a;
        }
    }
#pragma unroll
    for (int j = 0; j < NPB; j++)
        U[(size_t)(n0 + j) * (HID * EMB) + idx] = __float2bfloat16(acc[j]);
    // XB: NPB nodes x 16 columns per block (4 blocks cover all 64 columns)
    if (t < NPB * 16) {
        int j = t >> 4, oo = k * 16 + (t & 15);
        float s = 0.f;
        for (int i = 0; i < IN; i++) s += xin[(n0 + j) * IN + i] * bb2[i * EMB + oo];
        XB[(n0 + j) * EMB + oo] = s;
    }
}

// --- Edge gather + scatter: msg[e,o] = XB[src,o] + sum_h A[e,h]*U[src,h,o]; atomicAdd into AGG[dst,o]
__global__ void k_gather(const float* __restrict__ A, const __hip_bfloat16* __restrict__ U,
                         const float* __restrict__ XB,
                         const int* __restrict__ src, const int* __restrict__ dst,
                         float* __restrict__ AGG) {
    int e = blockIdx.x * (blockDim.x >> 6) + (threadIdx.x >> 6);
    if (e >= N_EDGES) return;
    int o = threadIdx.x & 63;
    int s = src[e], d = dst[e];
    float m = XB[s * EMB + o];
    const __hip_bfloat16* Ue = U + (size_t)s * (HID * EMB) + o;
    const float* Ae = A + e * HID;
#pragma unroll
    for (int h = 0; h < HID; h++) m += Ae[h] * __bfloat162float(Ue[h * EMB]);
    atomicAdd(&AGG[d * EMB + o], m);
}

// --- Node update, 4 nodes per 256-thread block; in-place safe (LDS-staged x).
//     X[n,o] = relu(AGG[n,o] + sum_i x[n,i]*root[i,o] + bias[o])
//     POOLING instance also does the global max pool (post-ReLU >= 0: uint atomicMax is order-preserving)
template <int IN, bool POOLING>
__global__ void k_update(const float* __restrict__ xin, const float* __restrict__ AGG,
                         const float* __restrict__ root, const float* __restrict__ bias,
                         const int* __restrict__ batch,
                         float* __restrict__ Xout, unsigned int* __restrict__ POOL) {
    int n0 = blockIdx.x * 4;
    __shared__ float xr[4][IN];
    for (int idx = threadIdx.x; idx < 4 * IN; idx += 256)
        xr[idx / IN][idx % IN] = xin[n0 * IN + idx];
    __syncthreads();
    int j = threadIdx.x >> 6, t = threadIdx.x & 63;
    int n = n0 + j;
    float s = AGG[n * EMB + t] + bias[t];
#pragma unroll
    for (int i = 0; i < IN; i++) s += xr[j][i] * root[i * EMB + t];
    s = fmaxf(s, 0.f);
    Xout[n * EMB + t] = s;
    if (POOLING) atomicMax(&POOL[batch[n] * EMB + t], __float_as_uint(s));
}

// --- Head: out[g] = (pooled[g]@lin0_w + lin0_b) @ lin1_w + lin1_b
__global__ void k_head(const float* __restrict__ POOL,
                       const float* __restrict__ l0w, const float* __restrict__ l0b,
                       const float* __restrict__ l1w, const float* __restrict__ l1b,
                       float* __restrict__ out) {
    __shared__ float P[NGRAPH * EMB];
    int t = threadIdx.x; // 64
    for (int k = 0; k < NGRAPH; k++) P[k * EMB + t] = POOL[k * EMB + t];
    __syncthreads();
    int g = t;
    float acc = l1b[0];
    for (int o2 = 0; o2 < EMB; o2++) {
        float h = l0b[o2];
        for (int o = 0; o < EMB; o++) h += P[g * EMB + o] * l0w[o * EMB + o2];
        acc += h * l1w[o2];
    }
    out[g] = acc;
}

extern "C" void kernel_launch(void* const* d_in, const int* in_sizes, int n_in,
                              void* d_out, int out_size, void* d_ws, size_t ws_size,
                              hipStream_t stream) {
    const float* x_p    = (const float*)d_in[0];
    const float* ea     = (const float*)d_in[2];
    const int*   eidx   = (const int*)d_in[4];
    const int*   batch  = (const int*)d_in[5];
    const float* nn0_w1 = (const float*)d_in[6];
    const float* nn0_b1 = (const float*)d_in[7];
    const float* nn0_w2 = (const float*)d_in[8];
    const float* nn0_b2 = (const float*)d_in[9];
    const float* nn1_w1 = (const float*)d_in[10];
    const float* nn1_b1 = (const float*)d_in[11];
    const float* nn1_w2 = (const float*)d_in[12];
    const float* nn1_b2 = (const float*)d_in[13];
    const float* root0  = (const float*)d_in[14];
    const float* bias0  = (const float*)d_in[15];
    const float* root1  = (const float*)d_in[16];
    const float* bias1  = (const float*)d_in[17];
    const float* root2  = (const float*)d_in[18];
    const float* bias2  = (const float*)d_in[19];
    const float* lin0_w = (const float*)d_in[20];
    const float* lin0_b = (const float*)d_in[21];
    const float* lin1_w = (const float*)d_in[22];
    const float* lin1_b = (const float*)d_in[23];

    const int* src = eidx;             // edge_index_p[0]
    const int* dst = eidx + N_EDGES;   // edge_index_p[1]

    // workspace layout, ~35 MB total
    char* ws = (char*)d_ws;
    float* A0   = (float*)ws;           ws += (size_t)N_EDGES * HID * 4;
    float* A1   = (float*)ws;           ws += (size_t)N_EDGES * HID * 4;
    __hip_bfloat16* U = (__hip_bfloat16*)ws; ws += (size_t)N_NODES * HID * EMB * 2;
    float* XB   = (float*)ws;           ws += (size_t)N_NODES * EMB * 4;
    float* X    = (float*)ws;           ws += (size_t)N_NODES * EMB * 4;
    float* AGG  = (float*)ws;           ws += (size_t)N_NODES * EMB * 4;
    float* POOL = (float*)ws;           ws += (size_t)NGRAPH * EMB * 4;

    const int PRE_GRID = (N_NODES / NPB) * 4;   // 5000
    const int UPD_GRID = N_NODES / 4;           // 2500

    // edge MLP hiddens for both MLPs (A1 shared by convs 1 & 2)
    k_edge_hidden<<<(N_EDGES + 127) / 128, 128, 0, stream>>>(ea, nn0_w1, nn0_b1, nn1_w1, nn1_b1, A0, A1);

    // ---- conv 0 (input x_p, F_NODE=32)
    k_precompute<F_NODE, false><<<PRE_GRID, 256, 0, stream>>>(x_p, nn0_w2, nn0_b2, U, XB, AGG, POOL);
    k_gather<<<(N_EDGES + 3) / 4, 256, 0, stream>>>(A0, U, XB, src, dst, AGG);
    k_update<F_NODE, false><<<UPD_GRID, 256, 0, stream>>>(x_p, AGG, root0, bias0, batch, X, (unsigned int*)POOL);

    // ---- conv 1 (input X, EMB=64)
    k_precompute<EMB, false><<<PRE_GRID, 256, 0, stream>>>(X, nn1_w2, nn1_b2, U, XB, AGG, POOL);
    k_gather<<<(N_EDGES + 3) / 4, 256, 0, stream>>>(A1, U, XB, src, dst, AGG);
    k_update<EMB, false><<<UPD_GRID, 256, 0, stream>>>(X, AGG, root1, bias1, batch, X, (unsigned int*)POOL);

    // ---- conv 2 (fused: POOL zeroing in precompute, max-pool in update)
    k_precompute<EMB, true><<<PRE_GRID, 256, 0, stream>>>(X, nn1_w2, nn1_b2, U, XB, AGG, POOL);
    k_gather<<<(N_EDGES + 3) / 4, 256, 0, stream>>>(A1, U, XB, src, dst, AGG);
    k_update<EMB, true><<<UPD_GRID, 256, 0, stream>>>(X, AGG, root2, bias2, batch, X, (unsigned int*)POOL);

    // ---- head
    k_head<<<1, 64, 0, stream>>>(POOL, lin0_w, lin0_b, lin1_w, lin1_b, (float*)d_out);
}